// Round 12
// baseline (127.541 us; speedup 1.0000x reference)
//
#include <hip/hip_runtime.h>
#include <hip/hip_bf16.h>

#define T_TOK 8192
#define DDIM  1024
#define NEXP  8
#define NT    16   // K-tiles of 64

typedef __attribute__((ext_vector_type(8))) short bf16x8;
typedef __attribute__((ext_vector_type(4))) float f32x4;

__device__ inline unsigned short f2bf(float f) {
  union { float f; unsigned int u; } a; a.f = f;
  unsigned int u = a.u;
  unsigned int r = (u + 0x7fffu + ((u >> 16) & 1u)) >> 16;  // RNE
  return (unsigned short)r;
}

__device__ inline void gload_lds16(const void* g, void* l) {
  __builtin_amdgcn_global_load_lds(
      (const __attribute__((address_space(1))) void*)g,
      (__attribute__((address_space(3))) void*)l, 16, 0, 0);
}

// ---------------- fused prep: blocks [0,2048) gate+cast-x, [2048,10240) cast W --
__global__ __launch_bounds__(256) void prep_kernel(
    const float* __restrict__ x, const float* __restrict__ gw,
    const float* __restrict__ ew,
    unsigned short* __restrict__ xb, unsigned short* __restrict__ Wb,
    int* __restrict__ e_of, float* __restrict__ w_of) {
  if (blockIdx.x >= 2048) {
    int i = (blockIdx.x - 2048) * 256 + threadIdx.x;   // < 2097152
    float4 v = reinterpret_cast<const float4*>(ew)[i];
    ushort4 o;
    o.x = f2bf(v.x); o.y = f2bf(v.y); o.z = f2bf(v.z); o.w = f2bf(v.w);
    reinterpret_cast<ushort4*>(Wb)[i] = o;
    return;
  }
  int t = blockIdx.x * 4 + (threadIdx.x >> 6);
  int lane = threadIdx.x & 63;
  const float4* xr = reinterpret_cast<const float4*>(x + (size_t)t * DDIM);
  ushort4* xbr = reinterpret_cast<ushort4*>(xb + (size_t)t * DDIM);
  float acc[NEXP];
#pragma unroll
  for (int e = 0; e < NEXP; ++e) acc[e] = 0.f;
#pragma unroll
  for (int c = 0; c < 4; ++c) {
    float4 xv = xr[c * 64 + lane];
    ushort4 o;
    o.x = f2bf(xv.x); o.y = f2bf(xv.y); o.z = f2bf(xv.z); o.w = f2bf(xv.w);
    xbr[c * 64 + lane] = o;
#pragma unroll
    for (int e = 0; e < NEXP; ++e) {
      float4 g = reinterpret_cast<const float4*>(gw + e * DDIM)[c * 64 + lane];
      acc[e] += xv.x * g.x + xv.y * g.y + xv.z * g.z + xv.w * g.w;
    }
  }
#pragma unroll
  for (int e = 0; e < NEXP; ++e) {
#pragma unroll
    for (int s = 32; s > 0; s >>= 1) acc[e] += __shfl_xor(acc[e], s);
  }
  if (lane == 0) {
    int e0 = 0; float v0 = acc[0];
#pragma unroll
    for (int e = 1; e < NEXP; ++e) if (acc[e] > v0) { v0 = acc[e]; e0 = e; }
    int e1 = (e0 == 0) ? 1 : 0; float v1 = acc[e1];
#pragma unroll
    for (int e = 0; e < NEXP; ++e)
      if (e != e0 && acc[e] > v1) { v1 = acc[e]; e1 = e; }
    float w1 = 1.f / (1.f + expf(v0 - v1));
    float w0 = 1.f - w1;
    e_of[2 * t] = e0; e_of[2 * t + 1] = e1;
    w_of[2 * t] = w0; w_of[2 * t + 1] = w1;
  }
}

// ---------------- counts: LDS histogram, 8 global atomics per block ----------------
__global__ __launch_bounds__(512) void count_kernel(
    const int* __restrict__ e_of, int* __restrict__ counts) {
  __shared__ int lc[NEXP];
  int tid = threadIdx.x;
  if (tid < NEXP) lc[tid] = 0;
  __syncthreads();
  atomicAdd(&lc[e_of[blockIdx.x * 512 + tid]], 1);
  __syncthreads();
  if (tid < NEXP) atomicAdd(&counts[tid], lc[tid]);
}

// ---------------- build row lists + per-row combine weight ----------------
__global__ __launch_bounds__(256) void build_kernel(
    const int* __restrict__ e_of, const float* __restrict__ w_of,
    const int* __restrict__ counts, int* __restrict__ cursor_rel,
    int* __restrict__ row_src, float* __restrict__ w_row) {
  __shared__ int lc[NEXP];
  __shared__ int lbase[NEXP];
  int tid = threadIdx.x;
  if (tid < NEXP) lc[tid] = 0;
  __syncthreads();
  int i0 = blockIdx.x * 512 + tid;
  int i1 = i0 + 256;
  int ea = e_of[i0], eb = e_of[i1];
  int ra = atomicAdd(&lc[ea], 1);
  int rb = atomicAdd(&lc[eb], 1);
  __syncthreads();
  if (tid < NEXP) {
    int off = 0;
    for (int ee = 0; ee < tid; ++ee) off += counts[ee];   // local prefix scan
    lbase[tid] = off + atomicAdd(&cursor_rel[tid], lc[tid]);
  }
  __syncthreads();
  int pa = lbase[ea] + ra;
  int pb = lbase[eb] + rb;
  row_src[pa] = i0 >> 1;
  w_row[pa] = w_of[i0];
  row_src[pb] = i1 >> 1;
  w_row[pb] = w_of[i1];
}

// ---------------- grouped GEMM + fused weighted scatter-add epilogue ------------
// R7-proven core (47 us, VGPR 64, 0 conflicts): 128x128 tile, BK=64, 4 waves,
// single-buffered 32 KB LDS, 4 blocks/CU ((256,4) is the ceiling — (256,5)
// spills acc, R10). Epilogue: out[tok] += w_row * acc via global f32 atomicAdd.
// Exactly 2 adds per output element from memset-0 — IEEE add is commutative,
// so the result is bitwise deterministic regardless of block order.
__global__ __launch_bounds__(256, 4) void gemm_kernel(
    const unsigned short* __restrict__ xb, const unsigned short* __restrict__ Wb,
    const int* __restrict__ row_src, const float* __restrict__ w_row,
    const int* __restrict__ counts, float* __restrict__ out) {
  // bijective XCD swizzle: 1088 = 8 * 136; consecutive wg share one XCD's L2.
  int orig = blockIdx.x;
  int wg = (orig & 7) * 136 + (orig >> 3);
  int mi = wg >> 3, ni = wg & 7;
  // derive expert e, m-block mj, row base from counts (BM = 128)
  int mj = mi, e = -1, base = 0;
#pragma unroll
  for (int ee = 0; ee < NEXP; ++ee) {
    int mb = (counts[ee] + 127) >> 7;
    if (e < 0) {
      if (mj < mb) e = ee;
      else { mj -= mb; base += counts[ee]; }
    }
  }
  if (e < 0) return;
  int ce = counts[e];
  int m0 = mj << 7;    // 128-row m-block
  int n0 = ni << 7;    // 128-col n-block

  __shared__ unsigned short As[128 * 64];  // 16 KB
  __shared__ unsigned short Bs[128 * 64];  // 16 KB

  int tid = threadIdx.x;
  int lane = tid & 63;
  int wid = tid >> 6;          // 0..3
  int wr = wid >> 1, wc = wid & 1;   // 2(M) x 2(N), wave tile 64x64

  // staging: wave wid owns chunks g = wid*4+j (8 rows each) for A and B
  int rl = lane >> 3, sl = lane & 7;
  int cperm = (sl ^ rl) * 8;   // pre-swizzled global element offset
  const unsigned short* We = Wb + (size_t)e * DDIM * DDIM;
  const unsigned short* asrc[4];
  const unsigned short* bsrc[4];
#pragma unroll
  for (int j = 0; j < 4; ++j) {
    int row = (wid * 4 + j) * 8 + rl;      // [0,128)
    int i = m0 + row; if (i > ce - 1) i = ce - 1;
    int tk = row_src[base + i];
    asrc[j] = xb + (size_t)tk * DDIM + cperm;
    bsrc[j] = We + (size_t)(n0 + row) * DDIM + cperm;
  }

  f32x4 acc[4][4];
#pragma unroll
  for (int m = 0; m < 4; ++m)
#pragma unroll
    for (int n = 0; n < 4; ++n) acc[m][n] = (f32x4){0.f, 0.f, 0.f, 0.f};

  int frow_a = wr * 64 + (lane & 15);
  int frow_b = wc * 64 + (lane & 15);
  int fchunk = lane >> 4;            // 0..3

  for (int t = 0; t < NT; ++t) {
    int koff = t * 64;
#pragma unroll
    for (int j = 0; j < 4; ++j)
      gload_lds16(asrc[j] + koff, &As[(wid * 4 + j) * 512]);
#pragma unroll
    for (int j = 0; j < 4; ++j)
      gload_lds16(bsrc[j] + koff, &Bs[(wid * 4 + j) * 512]);
    __syncthreads();   // compiler emits vmcnt(0) drain; other blocks hide it

#pragma unroll
    for (int ks = 0; ks < 2; ++ks) {
      int c = fchunk + ks * 4;
      bf16x8 af[4], bfr[4];
#pragma unroll
      for (int m = 0; m < 4; ++m) {
        int row = frow_a + m * 16;
        af[m] = *reinterpret_cast<const bf16x8*>(
            &As[row * 64 + ((c ^ (row & 7)) << 3)]);
      }
#pragma unroll
      for (int n = 0; n < 4; ++n) {
        int row = frow_b + n * 16;
        bfr[n] = *reinterpret_cast<const bf16x8*>(
            &Bs[row * 64 + ((c ^ (row & 7)) << 3)]);
      }
      __builtin_amdgcn_s_setprio(1);
#pragma unroll
      for (int m = 0; m < 4; ++m)
#pragma unroll
        for (int n = 0; n < 4; ++n)
          acc[m][n] = __builtin_amdgcn_mfma_f32_16x16x32_bf16(af[m], bfr[n], acc[m][n], 0, 0, 0);
      __builtin_amdgcn_s_setprio(0);
    }
    __syncthreads();   // all waves done reading before next stage overwrites
  }

  // fused epilogue: out[tok, col] += w_row * acc (C/D: col=lane&15, row=4*(lane>>4)+reg)
  int crow = (lane >> 4) * 4;
  int ccol = n0 + wc * 64 + (lane & 15);
#pragma unroll
  for (int m = 0; m < 4; ++m) {
#pragma unroll
    for (int r = 0; r < 4; ++r) {
      int grow = m0 + wr * 64 + m * 16 + crow + r;
      if (grow < ce) {
        int tok = row_src[base + grow];
        float wv = w_row[base + grow];
        float* orow = out + (size_t)tok * DDIM + ccol;
#pragma unroll
        for (int n = 0; n < 4; ++n)
          atomicAdd(&orow[n * 16], wv * acc[m][n][r]);
      }
    }
  }
}

extern "C" void kernel_launch(void* const* d_in, const int* in_sizes, int n_in,
                              void* d_out, int out_size, void* d_ws, size_t ws_size,
                              hipStream_t stream) {
  const float* x  = (const float*)d_in[0];
  const float* gw = (const float*)d_in[1];
  const float* ew = (const float*)d_in[2];
  float* out = (float*)d_out;
  char* ws = (char*)d_ws;

  unsigned short* xb = (unsigned short*)(ws);                    // 16 MB
  unsigned short* Wb = (unsigned short*)(ws + 16777216);         // 16 MB
  int*   e_of       = (int*)  (ws + 33554432);
  float* w_of       = (float*)(ws + 33619968);
  int*   row_src    = (int*)  (ws + 33685504);
  float* w_row      = (float*)(ws + 33751040);
  int*   counts     = (int*)  (ws + 33816576);   // 8 ints
  int*   cursor_rel = (int*)  (ws + 33816608);   // 8 ints

  hipMemsetAsync(counts, 0, 64, stream);                      // counts + cursor_rel
  hipMemsetAsync(out, 0, (size_t)out_size * 4, stream);       // accumulate target

  prep_kernel<<<10240, 256, 0, stream>>>(x, gw, ew, xb, Wb, e_of, w_of);
  count_kernel<<<32, 512, 0, stream>>>(e_of, counts);
  build_kernel<<<32, 256, 0, stream>>>(e_of, w_of, counts, cursor_rel, row_src, w_row);

  gemm_kernel<<<1088, 256, 0, stream>>>(xb, Wb, row_src, w_row, counts, out);
}

// Round 13
// 92.319 us; speedup vs baseline: 1.3815x; 1.3815x over previous
//
#include <hip/hip_runtime.h>
#include <hip/hip_bf16.h>

#define T_TOK 8192
#define DDIM  1024
#define NEXP  8
#define NT    16   // K-tiles of 64

typedef __attribute__((ext_vector_type(8))) short bf16x8;
typedef __attribute__((ext_vector_type(4))) float f32x4;

__device__ inline unsigned short f2bf(float f) {
  union { float f; unsigned int u; } a; a.f = f;
  unsigned int u = a.u;
  unsigned int r = (u + 0x7fffu + ((u >> 16) & 1u)) >> 16;  // RNE
  return (unsigned short)r;
}

__device__ inline float bf2f(unsigned short u) {
  union { unsigned int u; float f; } a; a.u = ((unsigned int)u) << 16;
  return a.f;
}

__device__ inline void gload_lds16(const void* g, void* l) {
  __builtin_amdgcn_global_load_lds(
      (const __attribute__((address_space(1))) void*)g,
      (__attribute__((address_space(3))) void*)l, 16, 0, 0);
}

// ---------------- fused prep: blocks [0,2048) gate+cast-x, [2048,10240) cast W --
__global__ __launch_bounds__(256) void prep_kernel(
    const float* __restrict__ x, const float* __restrict__ gw,
    const float* __restrict__ ew,
    unsigned short* __restrict__ xb, unsigned short* __restrict__ Wb,
    int* __restrict__ e_of, float* __restrict__ w_of) {
  if (blockIdx.x >= 2048) {
    int i = (blockIdx.x - 2048) * 256 + threadIdx.x;   // < 2097152
    float4 v = reinterpret_cast<const float4*>(ew)[i];
    ushort4 o;
    o.x = f2bf(v.x); o.y = f2bf(v.y); o.z = f2bf(v.z); o.w = f2bf(v.w);
    reinterpret_cast<ushort4*>(Wb)[i] = o;
    return;
  }
  int t = blockIdx.x * 4 + (threadIdx.x >> 6);
  int lane = threadIdx.x & 63;
  const float4* xr = reinterpret_cast<const float4*>(x + (size_t)t * DDIM);
  ushort4* xbr = reinterpret_cast<ushort4*>(xb + (size_t)t * DDIM);
  float acc[NEXP];
#pragma unroll
  for (int e = 0; e < NEXP; ++e) acc[e] = 0.f;
#pragma unroll
  for (int c = 0; c < 4; ++c) {
    float4 xv = xr[c * 64 + lane];
    ushort4 o;
    o.x = f2bf(xv.x); o.y = f2bf(xv.y); o.z = f2bf(xv.z); o.w = f2bf(xv.w);
    xbr[c * 64 + lane] = o;
#pragma unroll
    for (int e = 0; e < NEXP; ++e) {
      float4 g = reinterpret_cast<const float4*>(gw + e * DDIM)[c * 64 + lane];
      acc[e] += xv.x * g.x + xv.y * g.y + xv.z * g.z + xv.w * g.w;
    }
  }
#pragma unroll
  for (int e = 0; e < NEXP; ++e) {
#pragma unroll
    for (int s = 32; s > 0; s >>= 1) acc[e] += __shfl_xor(acc[e], s);
  }
  if (lane == 0) {
    int e0 = 0; float v0 = acc[0];
#pragma unroll
    for (int e = 1; e < NEXP; ++e) if (acc[e] > v0) { v0 = acc[e]; e0 = e; }
    int e1 = (e0 == 0) ? 1 : 0; float v1 = acc[e1];
#pragma unroll
    for (int e = 0; e < NEXP; ++e)
      if (e != e0 && acc[e] > v1) { v1 = acc[e]; e1 = e; }
    float w1 = 1.f / (1.f + expf(v0 - v1));
    float w0 = 1.f - w1;
    e_of[2 * t] = e0; e_of[2 * t + 1] = e1;
    w_of[2 * t] = w0; w_of[2 * t + 1] = w1;
  }
}

// ---------------- counts: LDS histogram, 8 global atomics per block ----------------
__global__ __launch_bounds__(512) void count_kernel(
    const int* __restrict__ e_of, int* __restrict__ counts) {
  __shared__ int lc[NEXP];
  int tid = threadIdx.x;
  if (tid < NEXP) lc[tid] = 0;
  __syncthreads();
  atomicAdd(&lc[e_of[blockIdx.x * 512 + tid]], 1);
  __syncthreads();
  if (tid < NEXP) atomicAdd(&counts[tid], lc[tid]);
}

// ---------------- build row lists (scan folded in: local offs + rel cursors) ----
__global__ __launch_bounds__(256) void build_kernel(
    const int* __restrict__ e_of, const int* __restrict__ counts,
    int* __restrict__ cursor_rel,
    int* __restrict__ row_src, int* __restrict__ tok_row) {
  __shared__ int lc[NEXP];
  __shared__ int lbase[NEXP];
  int tid = threadIdx.x;
  if (tid < NEXP) lc[tid] = 0;
  __syncthreads();
  int i0 = blockIdx.x * 512 + tid;
  int i1 = i0 + 256;
  int ea = e_of[i0], eb = e_of[i1];
  int ra = atomicAdd(&lc[ea], 1);
  int rb = atomicAdd(&lc[eb], 1);
  __syncthreads();
  if (tid < NEXP) {
    int off = 0;
    for (int ee = 0; ee < tid; ++ee) off += counts[ee];   // local prefix scan
    lbase[tid] = off + atomicAdd(&cursor_rel[tid], lc[tid]);
  }
  __syncthreads();
  int pa = lbase[ea] + ra;
  int pb = lbase[eb] + rb;
  row_src[pa] = i0 >> 1;
  tok_row[i0] = pa;
  row_src[pb] = i1 >> 1;
  tok_row[i1] = pb;
}

// ---------------- grouped GEMM: 128x128 tile, BK=64, 4 waves (2Mx2N) ------------
// R7/R11-proven structure (47 us, VGPR 64, 0 conflicts): single-buffered 32 KB
// LDS, stage -> __syncthreads (drain) -> 2x16 MFMA -> barrier; 4 blocks/CU
// cross-block TLP hides the drain. (256,4) is the occupancy ceiling — (256,5)
// caps the unified VGPR+AGPR budget below the ~128-reg need and spills (R10).
// Atomic-fused epilogue is slower (R12: uncoalesced 4B RMW, gemm 88 us).
// LDS swizzle: (row, k16) slot = c ^ (row&7), 128B rows (measured 0 conflicts).
// Stage: linear gload_lds dest + pre-permuted per-lane global source.
__global__ __launch_bounds__(256, 4) void gemm_kernel(
    const unsigned short* __restrict__ xb, const unsigned short* __restrict__ Wb,
    const int* __restrict__ row_src, const int* __restrict__ counts,
    unsigned short* __restrict__ Yb) {
  // bijective XCD swizzle: 1088 = 8 * 136; consecutive wg share one XCD's L2.
  int orig = blockIdx.x;
  int wg = (orig & 7) * 136 + (orig >> 3);
  int mi = wg >> 3, ni = wg & 7;
  // derive expert e, m-block mj, row base from counts (BM = 128)
  int mj = mi, e = -1, base = 0;
#pragma unroll
  for (int ee = 0; ee < NEXP; ++ee) {
    int mb = (counts[ee] + 127) >> 7;
    if (e < 0) {
      if (mj < mb) e = ee;
      else { mj -= mb; base += counts[ee]; }
    }
  }
  if (e < 0) return;
  int ce = counts[e];
  int m0 = mj << 7;    // 128-row m-block
  int n0 = ni << 7;    // 128-col n-block

  __shared__ unsigned short As[128 * 64];  // 16 KB
  __shared__ unsigned short Bs[128 * 64];  // 16 KB

  int tid = threadIdx.x;
  int lane = tid & 63;
  int wid = tid >> 6;          // 0..3
  int wr = wid >> 1, wc = wid & 1;   // 2(M) x 2(N), wave tile 64x64

  // staging: wave wid owns chunks g = wid*4+j (8 rows each) for A and B
  int rl = lane >> 3, sl = lane & 7;
  int cperm = (sl ^ rl) * 8;   // pre-swizzled global element offset
  const unsigned short* We = Wb + (size_t)e * DDIM * DDIM;
  const unsigned short* asrc[4];
  const unsigned short* bsrc[4];
#pragma unroll
  for (int j = 0; j < 4; ++j) {
    int row = (wid * 4 + j) * 8 + rl;      // [0,128)
    int i = m0 + row; if (i > ce - 1) i = ce - 1;
    int tk = row_src[base + i];
    asrc[j] = xb + (size_t)tk * DDIM + cperm;
    bsrc[j] = We + (size_t)(n0 + row) * DDIM + cperm;
  }

  f32x4 acc[4][4];
#pragma unroll
  for (int m = 0; m < 4; ++m)
#pragma unroll
    for (int n = 0; n < 4; ++n) acc[m][n] = (f32x4){0.f, 0.f, 0.f, 0.f};

  int frow_a = wr * 64 + (lane & 15);
  int frow_b = wc * 64 + (lane & 15);
  int fchunk = lane >> 4;            // 0..3

  for (int t = 0; t < NT; ++t) {
    int koff = t * 64;
#pragma unroll
    for (int j = 0; j < 4; ++j)
      gload_lds16(asrc[j] + koff, &As[(wid * 4 + j) * 512]);
#pragma unroll
    for (int j = 0; j < 4; ++j)
      gload_lds16(bsrc[j] + koff, &Bs[(wid * 4 + j) * 512]);
    __syncthreads();   // compiler emits vmcnt(0) drain; other blocks hide it

#pragma unroll
    for (int ks = 0; ks < 2; ++ks) {
      int c = fchunk + ks * 4;
      bf16x8 af[4], bfr[4];
#pragma unroll
      for (int m = 0; m < 4; ++m) {
        int row = frow_a + m * 16;
        af[m] = *reinterpret_cast<const bf16x8*>(
            &As[row * 64 + ((c ^ (row & 7)) << 3)]);
      }
#pragma unroll
      for (int n = 0; n < 4; ++n) {
        int row = frow_b + n * 16;
        bfr[n] = *reinterpret_cast<const bf16x8*>(
            &Bs[row * 64 + ((c ^ (row & 7)) << 3)]);
      }
      __builtin_amdgcn_s_setprio(1);
#pragma unroll
      for (int m = 0; m < 4; ++m)
#pragma unroll
        for (int n = 0; n < 4; ++n)
          acc[m][n] = __builtin_amdgcn_mfma_f32_16x16x32_bf16(af[m], bfr[n], acc[m][n], 0, 0, 0);
      __builtin_amdgcn_s_setprio(0);
    }
    __syncthreads();   // all waves done reading before next stage overwrites
  }

  // epilogue: C/D layout col=lane&15, row=(lane>>4)*4+reg
  int crow = (lane >> 4) * 4;
  int ccol = lane & 15;
#pragma unroll
  for (int m = 0; m < 4; ++m) {
#pragma unroll
    for (int r = 0; r < 4; ++r) {
      int grow = m0 + wr * 64 + m * 16 + crow + r;
      if (grow < ce) {
        unsigned short* yr = Yb + (size_t)(base + grow) * DDIM + n0 + wc * 64 + ccol;
#pragma unroll
        for (int n = 0; n < 4; ++n)
          yr[n * 16] = f2bf(acc[m][n][r]);
      }
    }
  }
}

// ---------------- combine: out[t] = w0*Y[p0] + w1*Y[p1], 8 tokens/block --------
__global__ __launch_bounds__(256) void combine_kernel(
    const unsigned short* __restrict__ Yb, const int* __restrict__ tok_row,
    const float* __restrict__ w_of, float* __restrict__ out) {
  int d = threadIdx.x * 4;
#pragma unroll
  for (int k = 0; k < 8; ++k) {
    int t = blockIdx.x * 8 + k;
    int p0 = tok_row[2 * t], p1 = tok_row[2 * t + 1];
    float w0 = w_of[2 * t], w1 = w_of[2 * t + 1];
    ushort4 y0 = reinterpret_cast<const ushort4*>(Yb + (size_t)p0 * DDIM + d)[0];
    ushort4 y1 = reinterpret_cast<const ushort4*>(Yb + (size_t)p1 * DDIM + d)[0];
    float4 o;
    o.x = w0 * bf2f(y0.x) + w1 * bf2f(y1.x);
    o.y = w0 * bf2f(y0.y) + w1 * bf2f(y1.y);
    o.z = w0 * bf2f(y0.z) + w1 * bf2f(y1.z);
    o.w = w0 * bf2f(y0.w) + w1 * bf2f(y1.w);
    reinterpret_cast<float4*>(out + (size_t)t * DDIM + d)[0] = o;
  }
}

extern "C" void kernel_launch(void* const* d_in, const int* in_sizes, int n_in,
                              void* d_out, int out_size, void* d_ws, size_t ws_size,
                              hipStream_t stream) {
  const float* x  = (const float*)d_in[0];
  const float* gw = (const float*)d_in[1];
  const float* ew = (const float*)d_in[2];
  float* out = (float*)d_out;
  char* ws = (char*)d_ws;

  unsigned short* xb = (unsigned short*)(ws);                    // 16 MB
  unsigned short* Wb = (unsigned short*)(ws + 16777216);         // 16 MB
  unsigned short* Yb = (unsigned short*)(ws + 33554432);         // 32 MB
  int*   e_of       = (int*)  (ws + 67108864);
  float* w_of       = (float*)(ws + 67174400);
  int*   row_src    = (int*)  (ws + 67239936);
  int*   tok_row    = (int*)  (ws + 67305472);
  int*   counts     = (int*)  (ws + 67371008);   // 8 ints
  int*   cursor_rel = (int*)  (ws + 67371040);   // 8 ints

  hipMemsetAsync(counts, 0, 64, stream);  // counts + cursor_rel

  prep_kernel<<<10240, 256, 0, stream>>>(x, gw, ew, xb, Wb, e_of, w_of);
  count_kernel<<<32, 512, 0, stream>>>(e_of, counts);
  build_kernel<<<32, 256, 0, stream>>>(e_of, counts, cursor_rel, row_src, tok_row);

  gemm_kernel<<<1088, 256, 0, stream>>>(xb, Wb, row_src, counts, Yb);

  combine_kernel<<<1024, 256, 0, stream>>>(Yb, tok_row, w_of, out);
}